// Round 4
// baseline (490.590 us; speedup 1.0000x reference)
//
#include <hip/hip_runtime.h>
#include <hip/hip_bf16.h>
#include <math.h>

namespace {

constexpr int MSTEPS = 60;
constexpr int NPTS   = 128;
constexpr int RPTS   = 32;
constexpr int BTOT   = 4096;   // RPTS * NPTS
constexpr int HID    = 128;
constexpr int PPB    = 8;      // paths per block; one wave per path
constexpr int NBLK   = BTOT / PPB;  // 512 blocks -> 2 per CU
constexpr int NCOL   = 40;     // 5 jet comps x 8 paths
constexpr int NCOLP  = 48;     // padded to 3 col tiles of 16
constexpr int KSTRB  = 136;    // B row stride (bf16 elems): 272B rows, 68 dwords (=4 mod 32)
constexpr int JSTRC  = 132;    // C row stride (f32): 132 dwords (=4 mod 32)

constexpr float F_T     = 1.5f;
constexpr float F_DT    = (float)(1.5 / 60.0);
constexpr float F_HALF  = (float)(0.5 * (1.5 / 60.0));
constexpr float F_SDT   = (float)0.15811388300841896659;  // sqrt(0.025)
constexpr float F_SHALF = (float)0.11180339887498948482;  // sqrt(0.0125)
constexpr float F_A     = (float)0.95393920141694565906;  // sqrt(1-0.3^2)
constexpr float F_IS2   = (float)0.70710678118654752440;
constexpr float F_R     = 0.02f;
constexpr float F_SIG   = 0.2f;
constexpr float F_SIGY  = 0.3f;
constexpr float F_RHO   = 0.3f;
constexpr float F_KY    = 1.2f;
constexpr float F_LBW   = 0.001f;
constexpr float F_LOGLBW = -6.90775527898213705205f;      // log(0.001)
constexpr float F_SA    = (float)(0.2 * 0.8);
constexpr float F_S2    = (float)(0.2 * 0.2);

typedef __attribute__((ext_vector_type(8))) short bf16x8;
typedef __attribute__((ext_vector_type(4))) float f32x4;

// RNE f32->bf16 (used once, for W2 split at kernel start)
__device__ __forceinline__ unsigned short f2bf(float x) {
  union { float f; unsigned u; } v; v.f = x;
  unsigned r = v.u + 0x7fffu + ((v.u >> 16) & 1u);
  return (unsigned short)(r >> 16);
}
__device__ __forceinline__ float bf2f(unsigned short h) {
  union { float f; unsigned u; } v; v.u = ((unsigned)h) << 16; return v.f;
}

// fast tanh: 1 - 2/(e^{2x}+1)
__device__ __forceinline__ float ftanh(float x) {
  float e = __expf(2.0f * x);
  return 1.0f - 2.0f / (e + 1.0f);
}

// ---- 2nd-order jet: value, d/dW0, d/dY0, d2/dW0^2, d2/dW0dY0 ----
struct Jet { float v, w, y, ww, wy; };

__device__ __forceinline__ Jet jmul(const Jet& a, const Jet& b) {
  Jet r;
  r.v  = a.v * b.v;
  r.w  = a.v * b.w + a.w * b.v;
  r.y  = a.v * b.y + a.y * b.v;
  r.ww = a.v * b.ww + 2.0f * a.w * b.w + a.ww * b.v;
  r.wy = a.v * b.wy + a.w * b.y + a.y * b.w + a.wy * b.v;
  return r;
}

__device__ __forceinline__ Jet jexp(const Jet& a) {
  float e = __expf(a.v);
  Jet r;
  r.v  = e;
  r.w  = e * a.w;
  r.y  = e * a.y;
  r.ww = e * (a.ww + a.w * a.w);
  r.wy = e * (a.wy + a.w * a.y);
  return r;
}

__device__ __forceinline__ Jet jtanh(const Jet& a) {
  float t  = ftanh(a.v);
  float f1 = 1.0f - t * t;
  float f2 = -2.0f * t * f1;
  Jet r;
  r.v  = t;
  r.w  = f1 * a.w;
  r.y  = f1 * a.y;
  r.ww = f1 * a.ww + f2 * a.w * a.w;
  r.wy = f1 * a.wy + f2 * a.w * a.y;
  return r;
}

__device__ __forceinline__ Jet jstep(const Jet& base, const Jet& d, float cdt,
                                     const Jet& p, float cw) {
  Jet r;
  r.v  = base.v  + d.v  * cdt + p.v  * cw;
  r.w  = base.w  + d.w  * cdt + p.w  * cw;
  r.y  = base.y  + d.y  * cdt + p.y  * cw;
  r.ww = base.ww + d.ww * cdt + p.ww * cw;
  r.wy = base.wy + d.wy * cdt + p.wy * cw;
  return r;
}

__device__ __forceinline__ Jet ydec(const Jet& Y, float dt, float add) {
  Jet r;
  r.v  = Y.v  - F_KY * Y.v  * dt + add;
  r.w  = Y.w  - F_KY * Y.w  * dt;
  r.y  = Y.y  - F_KY * Y.y  * dt;
  r.ww = Y.ww - F_KY * Y.ww * dt;
  r.wy = Y.wy - F_KY * Y.wy * dt;
  return r;
}

__device__ __forceinline__ Jet driftvar(const Jet& pY, const Jet& pp) {
  Jet r;
  r.v  = F_R + F_SA * pY.v  - 0.5f * F_S2 * pp.v;
  r.w  =       F_SA * pY.w  - 0.5f * F_S2 * pp.w;
  r.y  =       F_SA * pY.y  - 0.5f * F_S2 * pp.y;
  r.ww =       F_SA * pY.ww - 0.5f * F_S2 * pp.ww;
  r.wy =       F_SA * pY.wy - 0.5f * F_S2 * pp.wy;
  return r;
}

} // namespace

// Block = 8 paths x 64 lanes (one wave per path). Lane owns hidden units {2tl, 2tl+1}.
// Layer 2: C[128j][48col] = W2^T . H via split-bf16 MFMA; wave wv owns C row tile wv*16.
// B (h-jets hi/lo) and C are DISJOINT -> only 2 barriers per eval.
__global__ __launch_bounds__(512, 4) void ppgdpo_sim_kernel(
    const float* __restrict__ Wp, const float* __restrict__ Yp,
    const float* __restrict__ w1, const float* __restrict__ b1,
    const float* __restrict__ w2, const float* __restrict__ b2,
    const float* __restrict__ w3, const float* __restrict__ b3,
    const float* __restrict__ noise, float* __restrict__ ws) {
  __shared__ __align__(16) unsigned short Bh[NCOLP * KSTRB];  // 13,056 B
  __shared__ __align__(16) unsigned short Bl[NCOLP * KSTRB];  // 13,056 B
  __shared__ __align__(16) float Cls[NCOLP * JSTRC];          // 25,344 B

  const int t  = threadIdx.x;
  const int p  = t >> 6;           // path in block == wave id
  const int tl = t & 63;           // lane in wave
  const int wv = p;
  const int ln = tl;
  const int b0 = blockIdx.x * PPB + p;
  const int b  = __builtin_amdgcn_readfirstlane(b0);   // wave-uniform -> scalar loads
  const int i  = b & (NPTS - 1);

  // ---- W2 -> per-wave A fragments in registers (RNE hi/lo split, done once) ----
  // A[j][k] = w2[k*128+j]; lane holds row j = wv*16+(ln&15), k = kt*32+(ln>>4)*8+q
  bf16x8 Ah[4], Al[4];
  {
    const int arow = wv * 16 + (ln & 15);
    const int kg   = (ln >> 4) * 8;
#pragma unroll
    for (int kt = 0; kt < 4; ++kt) {
#pragma unroll
      for (int q = 0; q < 8; ++q) {
        float wval = w2[(kt * 32 + kg + q) * HID + arow];
        unsigned short hi = f2bf(wval);
        unsigned short lo = f2bf(wval - bf2f(hi));
        Ah[kt][q] = (short)hi;
        Al[kt][q] = (short)lo;
      }
    }
  }

  // per-lane layer-1/3 weights for owned units j0=2tl, j0+1
  const int j0 = 2 * tl;
  float w10[2], w11[2], w12[2], b1a[2], b2a[2], w3a[2];
  {
    float2 v;
    v = *(const float2*)(w1 + 0 * HID + j0); w10[0] = v.x; w10[1] = v.y;
    v = *(const float2*)(w1 + 1 * HID + j0); w11[0] = v.x; w11[1] = v.y;
    v = *(const float2*)(w1 + 2 * HID + j0); w12[0] = v.x; w12[1] = v.y;
    v = *(const float2*)(b1 + j0);           b1a[0] = v.x; b1a[1] = v.y;
    v = *(const float2*)(b2 + j0);           b2a[0] = v.x; b2a[1] = v.y;
    v = *(const float2*)(w3 + j0);           w3a[0] = v.x; w3a[1] = v.y;
  }
  const float b3r = b3[0];

  unsigned* const Bh32 = (unsigned*)Bh;
  unsigned* const Bl32 = (unsigned*)Bl;

  auto mlp = [&](const Jet& Win, float tsub, const Jet& Yin) -> Jet {
    // ---- layer 1: 2 owned units; truncation hi/lo split; packed u32 writes ----
    Jet h[2];
#pragma unroll
    for (int jt = 0; jt < 2; ++jt) {
      Jet a;
      a.v  = fmaf(w10[jt], Win.v, fmaf(w11[jt], tsub, fmaf(w12[jt], Yin.v, b1a[jt])));
      a.w  = fmaf(w10[jt], Win.w,  w12[jt] * Yin.w);
      a.y  = fmaf(w10[jt], Win.y,  w12[jt] * Yin.y);
      a.ww = fmaf(w10[jt], Win.ww, w12[jt] * Yin.ww);
      a.wy = fmaf(w10[jt], Win.wy, w12[jt] * Yin.wy);
      h[jt] = jtanh(a);
    }
    {
      float h0v[5] = {h[0].v, h[0].w, h[0].y, h[0].ww, h[0].wy};
      float h1v[5] = {h[1].v, h[1].w, h[1].y, h[1].ww, h[1].wy};
#pragma unroll
      for (int c = 0; c < 5; ++c) {
        unsigned u0 = __float_as_uint(h0v[c]);
        unsigned u1 = __float_as_uint(h1v[c]);
        unsigned hiw = (u0 >> 16) | (u1 & 0xffff0000u);
        float l0 = h0v[c] - __uint_as_float(u0 & 0xffff0000u);
        float l1 = h1v[c] - __uint_as_float(u1 & 0xffff0000u);
        unsigned low = (__float_as_uint(l0) >> 16) | (__float_as_uint(l1) & 0xffff0000u);
        const int d = (c * PPB + p) * (KSTRB / 2) + tl;   // lane-consecutive dwords
        Bh32[d] = hiw;
        Bl32[d] = low;
      }
    }
    __syncthreads();   // sync1: B complete (also orders prev gather reads before C write)
    // ---- MFMA: 3 col tiles x 4 k tiles x 3 split products ----
    const int bx  = ln & 15;
    const int bgo = (ln >> 4) * 8;
    const int crow = wv * 16 + (ln >> 4) * 4;
#pragma unroll
    for (int ct = 0; ct < 3; ++ct) {
      f32x4 a_ = {0.f, 0.f, 0.f, 0.f};
#pragma unroll
      for (int kt = 0; kt < 4; ++kt) {
        const int boff = (ct * 16 + bx) * KSTRB + kt * 32 + bgo;
        bf16x8 bh = *reinterpret_cast<const bf16x8*>(Bh + boff);
        bf16x8 bl = *reinterpret_cast<const bf16x8*>(Bl + boff);
        a_ = __builtin_amdgcn_mfma_f32_16x16x32_bf16(Ah[kt], bh, a_, 0, 0, 0);
        a_ = __builtin_amdgcn_mfma_f32_16x16x32_bf16(Ah[kt], bl, a_, 0, 0, 0);
        a_ = __builtin_amdgcn_mfma_f32_16x16x32_bf16(Al[kt], bh, a_, 0, 0, 0);
      }
      *reinterpret_cast<f32x4*>(Cls + (ct * 16 + bx) * JSTRC + crow) = a_;
    }
    __syncthreads();   // sync2: C complete
    // ---- gather a2 jets (float2 per comp) + tanh + layer 3 ----
    float2 cv[5];
#pragma unroll
    for (int c = 0; c < 5; ++c)
      cv[c] = *(const float2*)(Cls + (c * PPB + p) * JSTRC + j0);
    float s[5] = {0.f, 0.f, 0.f, 0.f, 0.f};
#pragma unroll
    for (int jt = 0; jt < 2; ++jt) {
      Jet a2;
      a2.v  = (jt ? cv[0].y : cv[0].x) + b2a[jt];
      a2.w  = jt ? cv[1].y : cv[1].x;
      a2.y  = jt ? cv[2].y : cv[2].x;
      a2.ww = jt ? cv[3].y : cv[3].x;
      a2.wy = jt ? cv[4].y : cv[4].x;
      Jet hh = jtanh(a2);
      s[0] = fmaf(hh.v,  w3a[jt], s[0]);
      s[1] = fmaf(hh.w,  w3a[jt], s[1]);
      s[2] = fmaf(hh.y,  w3a[jt], s[2]);
      s[3] = fmaf(hh.ww, w3a[jt], s[3]);
      s[4] = fmaf(hh.wy, w3a[jt], s[4]);
    }
#pragma unroll
    for (int off = 32; off >= 1; off >>= 1) {
#pragma unroll
      for (int c = 0; c < 5; ++c) s[c] += __shfl_xor(s[c], off, 64);
    }
    Jet pi;
    pi.v = s[0] + b3r; pi.w = s[1]; pi.y = s[2]; pi.ww = s[3]; pi.wy = s[4];
    return pi;
  };

  // ---- initial state jets ----
  const float W0 = Wp[i];
  Jet L;
  L.v = __logf(fmaxf(W0, F_LBW));
  L.w = 1.0f / W0;
  L.y = 0.0f;
  L.ww = -1.0f / (W0 * W0);
  L.wy = 0.0f;
  Jet Yj;
  Yj.v = Yp[i]; Yj.w = 0.0f; Yj.y = 1.0f; Yj.ww = 0.0f; Yj.wy = 0.0f;
  float tmt = F_T;

  for (int m = 0; m < MSTEPS; ++m) {
    const float* nz = noise + (size_t)(m * 4) * BTOT + b;
    float z1b = nz[0];
    float z2b = nz[BTOT];
    float z1n = nz[2 * BTOT];
    float z2n = nz[3 * BTOT];
    float zWb = z1b, zYb = F_RHO * z1b + F_A * z2b;
    float zWn = z1n, zYn = F_RHO * z1n + F_A * z2n;
    float zWh1 = (zWb + zWn) * F_IS2, zYh1 = (zYb + zYn) * F_IS2;
    float zWh2 = (zWb - zWn) * F_IS2, zYh2 = (zYb - zYn) * F_IS2;

    Jet Win  = jexp(L);
    Jet pi_t = mlp(Win, tmt, Yj);

    Jet pY = jmul(pi_t, Yj);
    Jet pp = jmul(pi_t, pi_t);
    Jet dv = driftvar(pY, pp);

    float cWc  = F_SIG * (F_SDT * zWb);
    Jet lWc = jstep(L, dv, F_DT, pi_t, cWc);                      // coarse
    Jet Yc  = ydec(Yj, F_DT, F_SIGY * (F_SDT * zYb));

    float cWh1 = F_SIG * (F_SHALF * zWh1);
    Jet lWh = jstep(L, dv, F_HALF, pi_t, cWh1);                   // half 1
    Jet Yh  = ydec(Yj, F_HALF, F_SIGY * (F_SHALF * zYh1));

    Jet pih = mlp(jexp(lWh), tmt - F_HALF, Yh);                   // half 2
    Jet pYh = jmul(pih, Yh);
    Jet pph = jmul(pih, pih);
    Jet dvh = driftvar(pYh, pph);
    float cWh2 = F_SIG * (F_SHALF * zWh2);
    Jet lWf = jstep(lWh, dvh, F_HALF, pih, cWh2);
    Jet Yf  = ydec(Yh, F_HALF, F_SIGY * (F_SHALF * zYh2));

    // Richardson combination
    Jet raw, Yn;
    raw.v  = 2.0f * lWf.v  - lWc.v;
    raw.w  = 2.0f * lWf.w  - lWc.w;
    raw.y  = 2.0f * lWf.y  - lWc.y;
    raw.ww = 2.0f * lWf.ww - lWc.ww;
    raw.wy = 2.0f * lWf.wy - lWc.wy;
    Yn.v  = 2.0f * Yf.v  - Yc.v;
    Yn.w  = 2.0f * Yf.w  - Yc.w;
    Yn.y  = 2.0f * Yf.y  - Yc.y;
    Yn.ww = 2.0f * Yf.ww - Yc.ww;
    Yn.wy = 2.0f * Yf.wy - Yc.wy;

    // wealth floor: below log(LB_W) clamp value, zero derivatives
    bool ok = raw.v > F_LOGLBW;
    L.v  = ok ? raw.v  : F_LOGLBW;
    L.w  = ok ? raw.w  : 0.0f;
    L.y  = ok ? raw.y  : 0.0f;
    L.ww = ok ? raw.ww : 0.0f;
    L.wy = ok ? raw.wy : 0.0f;
    Yj = Yn;
    tmt -= F_DT;
  }

  // U = -0.25*exp(-4L); per-path dU/dW0, d2U/dW0^2, d2U/dW0dY0
  if (tl == 0) {
    float g = __expf(-4.0f * L.v);
    ws[b]            = g * L.w;
    ws[BTOT + b]     = g * (L.ww - 4.0f * L.w * L.w);
    ws[2 * BTOT + b] = g * (L.wy - 4.0f * L.w * L.y);
  }
}

__global__ void ppgdpo_reduce_kernel(const float* __restrict__ ws,
                                     const float* __restrict__ Wp,
                                     const float* __restrict__ Yp,
                                     float* __restrict__ out) {
  int i = threadIdx.x;  // 128 threads
  float sU = 0.f, sWW = 0.f, sWY = 0.f;
  for (int r = 0; r < RPTS; ++r) {
    int b = r * NPTS + i;
    sU  += ws[b];
    sWW += ws[BTOT + b];
    sWY += ws[2 * BTOT + b];
  }
  float lam = sU  * (1.0f / 32768.0f);
  float dW  = sWW * (1.0f / 1048576.0f);
  float dY  = sWY * (1.0f / 1048576.0f);

  float mu    = F_SIG * (0.8f * Yp[i]);
  float coeff = -1.0f / (Wp[i] * dW + 1e-8f);
  float myo   = coeff * (lam * (mu / F_S2));
  float hedge = coeff * ((float)(0.2 * 0.3 * 0.3) * dY / F_S2);
  float pi = myo + hedge;
  pi = fminf(fmaxf(pi, -2.0f), 2.0f);
  out[i] = pi;
}

extern "C" void kernel_launch(void* const* d_in, const int* in_sizes, int n_in,
                              void* d_out, int out_size, void* d_ws, size_t ws_size,
                              hipStream_t stream) {
  const float* W     = (const float*)d_in[0];
  const float* Y     = (const float*)d_in[2];
  const float* w1    = (const float*)d_in[3];
  const float* b1    = (const float*)d_in[4];
  const float* w2    = (const float*)d_in[5];
  const float* b2    = (const float*)d_in[6];
  const float* w3    = (const float*)d_in[7];
  const float* b3    = (const float*)d_in[8];
  const float* noise = (const float*)d_in[9];
  float* ws = (float*)d_ws;
  float* out = (float*)d_out;

  ppgdpo_sim_kernel<<<dim3(NBLK), dim3(512), 0, stream>>>(
      W, Y, w1, b1, w2, b2, w3, b3, noise, ws);
  ppgdpo_reduce_kernel<<<dim3(1), dim3(128), 0, stream>>>(ws, W, Y, out);
}

// Round 5
// 324.874 us; speedup vs baseline: 1.5101x; 1.5101x over previous
//
#include <hip/hip_runtime.h>
#include <hip/hip_bf16.h>
#include <math.h>

namespace {

constexpr int MSTEPS = 60;
constexpr int NPTS   = 128;
constexpr int RPTS   = 32;
constexpr int BTOT   = 4096;   // RPTS * NPTS
constexpr int HID    = 128;
constexpr int PPB    = 8;      // paths per block; one wave per path
constexpr int NBLK   = BTOT / PPB;  // 512 blocks -> 2 per CU
constexpr int NCOLP  = 48;     // 40 cols (5 comps x 8 paths) padded to 3 tiles of 16
constexpr int KSTRB  = 136;    // B row stride (bf16): 272B rows, 68 dwords (=4 mod 32)
constexpr int JSTRC  = 132;    // C row stride (f32): =4 mod 32

constexpr float F_T     = 1.5f;
constexpr float F_DT    = (float)(1.5 / 60.0);
constexpr float F_HALF  = (float)(0.5 * (1.5 / 60.0));
constexpr float F_SDT   = (float)0.15811388300841896659;  // sqrt(0.025)
constexpr float F_SHALF = (float)0.11180339887498948482;  // sqrt(0.0125)
constexpr float F_A     = (float)0.95393920141694565906;  // sqrt(1-0.3^2)
constexpr float F_IS2   = (float)0.70710678118654752440;
constexpr float F_R     = 0.02f;
constexpr float F_SIG   = 0.2f;
constexpr float F_SIGY  = 0.3f;
constexpr float F_RHO   = 0.3f;
constexpr float F_KY    = 1.2f;
constexpr float F_LBW   = 0.001f;
constexpr float F_LOGLBW = -6.90775527898213705205f;      // log(0.001)
constexpr float F_SA    = (float)(0.2 * 0.8);
constexpr float F_S2    = (float)(0.2 * 0.2);

typedef __attribute__((ext_vector_type(8))) short bf16x8;
typedef __attribute__((ext_vector_type(4))) float f32x4;

// RNE f32->bf16
__device__ __forceinline__ unsigned short f2bf(float x) {
  union { float f; unsigned u; } v; v.f = x;
  unsigned r = v.u + 0x7fffu + ((v.u >> 16) & 1u);
  return (unsigned short)(r >> 16);
}
__device__ __forceinline__ float bf2f(unsigned short h) {
  union { float f; unsigned u; } v; v.u = ((unsigned)h) << 16; return v.f;
}

// fast tanh: 1 - 2/(e^{2x}+1)
__device__ __forceinline__ float ftanh(float x) {
  float e = __expf(2.0f * x);
  return 1.0f - 2.0f / (e + 1.0f);
}

// x + dpp_perm(x); bound_ctrl=1 -> invalid source lanes contribute 0
template <int CTRL>
__device__ __forceinline__ float dpp_add(float x) {
  int y = __builtin_amdgcn_update_dpp(0, __float_as_int(x), CTRL, 0xf, 0xf, true);
  return x + __int_as_float(y);
}

// wave64 all-sum, result broadcast via readlane (VALU/SALU only -- no LDS pipe)
__device__ __forceinline__ float wave_allsum(float x) {
  x = dpp_add<0xB1>(x);   // quad_perm [1,0,3,2]  (xor 1)
  x = dpp_add<0x4E>(x);   // quad_perm [2,3,0,1]  (xor 2)
  x = dpp_add<0x124>(x);  // row_ror:4
  x = dpp_add<0x128>(x);  // row_ror:8  -> every lane has its row-of-16 sum
  x = dpp_add<0x142>(x);  // row_bcast15: row1 += row0, row3 += row2
  x = dpp_add<0x143>(x);  // row_bcast31: lanes 48-63 have the full 64-lane sum
  return __int_as_float(__builtin_amdgcn_readlane(__float_as_int(x), 63));
}

// ---- 2nd-order jet: value, d/dW0, d/dY0, d2/dW0^2, d2/dW0dY0 ----
struct Jet { float v, w, y, ww, wy; };

__device__ __forceinline__ Jet jmul(const Jet& a, const Jet& b) {
  Jet r;
  r.v  = a.v * b.v;
  r.w  = a.v * b.w + a.w * b.v;
  r.y  = a.v * b.y + a.y * b.v;
  r.ww = a.v * b.ww + 2.0f * a.w * b.w + a.ww * b.v;
  r.wy = a.v * b.wy + a.w * b.y + a.y * b.w + a.wy * b.v;
  return r;
}

__device__ __forceinline__ Jet jexp(const Jet& a) {
  float e = __expf(a.v);
  Jet r;
  r.v  = e;
  r.w  = e * a.w;
  r.y  = e * a.y;
  r.ww = e * (a.ww + a.w * a.w);
  r.wy = e * (a.wy + a.w * a.y);
  return r;
}

__device__ __forceinline__ Jet jtanh(const Jet& a) {
  float t  = ftanh(a.v);
  float f1 = 1.0f - t * t;
  float f2 = -2.0f * t * f1;
  Jet r;
  r.v  = t;
  r.w  = f1 * a.w;
  r.y  = f1 * a.y;
  r.ww = f1 * a.ww + f2 * a.w * a.w;
  r.wy = f1 * a.wy + f2 * a.w * a.y;
  return r;
}

__device__ __forceinline__ Jet jstep(const Jet& base, const Jet& d, float cdt,
                                     const Jet& p, float cw) {
  Jet r;
  r.v  = base.v  + d.v  * cdt + p.v  * cw;
  r.w  = base.w  + d.w  * cdt + p.w  * cw;
  r.y  = base.y  + d.y  * cdt + p.y  * cw;
  r.ww = base.ww + d.ww * cdt + p.ww * cw;
  r.wy = base.wy + d.wy * cdt + p.wy * cw;
  return r;
}

__device__ __forceinline__ Jet ydec(const Jet& Y, float dt, float add) {
  Jet r;
  r.v  = Y.v  - F_KY * Y.v  * dt + add;
  r.w  = Y.w  - F_KY * Y.w  * dt;
  r.y  = Y.y  - F_KY * Y.y  * dt;
  r.ww = Y.ww - F_KY * Y.ww * dt;
  r.wy = Y.wy - F_KY * Y.wy * dt;
  return r;
}

__device__ __forceinline__ Jet driftvar(const Jet& pY, const Jet& pp) {
  Jet r;
  r.v  = F_R + F_SA * pY.v  - 0.5f * F_S2 * pp.v;
  r.w  =       F_SA * pY.w  - 0.5f * F_S2 * pp.w;
  r.y  =       F_SA * pY.y  - 0.5f * F_S2 * pp.y;
  r.ww =       F_SA * pY.ww - 0.5f * F_S2 * pp.ww;
  r.wy =       F_SA * pY.wy - 0.5f * F_S2 * pp.wy;
  return r;
}

} // namespace

// Block = 8 paths x 64 lanes (one wave per path). Lane owns hidden units {2tl, 2tl+1}.
// Layer 2: C[128j][48col] = (W2hi+W2lo)^T . Hbf16 via MFMA; wave wv owns row tile wv*16.
// H stored hi-only (RNE bf16); W2 keeps hi/lo split in registers (2 MFMAs per B block).
__global__ __launch_bounds__(512, 4) void ppgdpo_sim_kernel(
    const float* __restrict__ Wp, const float* __restrict__ Yp,
    const float* __restrict__ w1, const float* __restrict__ b1,
    const float* __restrict__ w2, const float* __restrict__ b2,
    const float* __restrict__ w3, const float* __restrict__ b3,
    const float* __restrict__ noise, float* __restrict__ ws) {
  __shared__ __align__(16) unsigned short Bh[NCOLP * KSTRB];  // 13,056 B
  __shared__ __align__(16) float Cls[NCOLP * JSTRC];          // 25,344 B

  const int t  = threadIdx.x;
  const int p  = t >> 6;           // path in block == wave id
  const int tl = t & 63;           // lane in wave
  const int wv = p;
  const int ln = tl;
  const int b0 = blockIdx.x * PPB + p;
  const int b  = __builtin_amdgcn_readfirstlane(b0);   // wave-uniform -> scalar loads
  const int i  = b & (NPTS - 1);

  // ---- W2 -> per-wave A fragments in registers (RNE hi/lo split, once) ----
  // A[j][k] = w2[k*128+j]; lane holds row j = wv*16+(ln&15), k = kt*32+(ln>>4)*8+q
  bf16x8 Ah[4], Al[4];
  {
    const int arow = wv * 16 + (ln & 15);
    const int kg   = (ln >> 4) * 8;
#pragma unroll
    for (int kt = 0; kt < 4; ++kt) {
#pragma unroll
      for (int q = 0; q < 8; ++q) {
        float wval = w2[(kt * 32 + kg + q) * HID + arow];
        unsigned short hi = f2bf(wval);
        unsigned short lo = f2bf(wval - bf2f(hi));
        Ah[kt][q] = (short)hi;
        Al[kt][q] = (short)lo;
      }
    }
  }

  // per-lane layer-1/3 weights for owned units j0=2tl, j0+1
  const int j0 = 2 * tl;
  float w10[2], w11[2], w12[2], b1a[2], b2a[2], w3a[2];
  {
    float2 v;
    v = *(const float2*)(w1 + 0 * HID + j0); w10[0] = v.x; w10[1] = v.y;
    v = *(const float2*)(w1 + 1 * HID + j0); w11[0] = v.x; w11[1] = v.y;
    v = *(const float2*)(w1 + 2 * HID + j0); w12[0] = v.x; w12[1] = v.y;
    v = *(const float2*)(b1 + j0);           b1a[0] = v.x; b1a[1] = v.y;
    v = *(const float2*)(b2 + j0);           b2a[0] = v.x; b2a[1] = v.y;
    v = *(const float2*)(w3 + j0);           w3a[0] = v.x; w3a[1] = v.y;
  }
  const float b3r = b3[0];

  unsigned* const Bh32 = (unsigned*)Bh;

  auto mlp = [&](const Jet& Win, float tsub, const Jet& Yin) -> Jet {
    // ---- layer 1: 2 owned units; RNE bf16 pack; one u32 LDS write per comp ----
    Jet h[2];
#pragma unroll
    for (int jt = 0; jt < 2; ++jt) {
      Jet a;
      a.v  = fmaf(w10[jt], Win.v, fmaf(w11[jt], tsub, fmaf(w12[jt], Yin.v, b1a[jt])));
      a.w  = fmaf(w10[jt], Win.w,  w12[jt] * Yin.w);
      a.y  = fmaf(w10[jt], Win.y,  w12[jt] * Yin.y);
      a.ww = fmaf(w10[jt], Win.ww, w12[jt] * Yin.ww);
      a.wy = fmaf(w10[jt], Win.wy, w12[jt] * Yin.wy);
      h[jt] = jtanh(a);
    }
    {
      float h0v[5] = {h[0].v, h[0].w, h[0].y, h[0].ww, h[0].wy};
      float h1v[5] = {h[1].v, h[1].w, h[1].y, h[1].ww, h[1].wy};
#pragma unroll
      for (int c = 0; c < 5; ++c) {
        unsigned u0 = __float_as_uint(h0v[c]);
        unsigned u1 = __float_as_uint(h1v[c]);
        unsigned r0 = (u0 + 0x7fffu + ((u0 >> 16) & 1u)) >> 16;
        unsigned r1 = (u1 + 0x7fffu + ((u1 >> 16) & 1u)) & 0xffff0000u;
        Bh32[(c * PPB + p) * (KSTRB / 2) + tl] = r0 | r1;  // lane-consecutive dwords
      }
    }
    __syncthreads();   // sync1: B complete (also orders prev gather vs this C-write)
    // ---- MFMA: 3 col tiles x 4 k tiles x 2 split products (Ah+Al vs Bh) ----
    const int bx  = ln & 15;
    const int bgo = (ln >> 4) * 8;
    const int crow = wv * 16 + (ln >> 4) * 4;
#pragma unroll
    for (int ct = 0; ct < 3; ++ct) {
      f32x4 a_ = {0.f, 0.f, 0.f, 0.f};
#pragma unroll
      for (int kt = 0; kt < 4; ++kt) {
        const int boff = (ct * 16 + bx) * KSTRB + kt * 32 + bgo;
        bf16x8 bh = *reinterpret_cast<const bf16x8*>(Bh + boff);
        a_ = __builtin_amdgcn_mfma_f32_16x16x32_bf16(Ah[kt], bh, a_, 0, 0, 0);
        a_ = __builtin_amdgcn_mfma_f32_16x16x32_bf16(Al[kt], bh, a_, 0, 0, 0);
      }
      *reinterpret_cast<f32x4*>(Cls + (ct * 16 + bx) * JSTRC + crow) = a_;
    }
    __syncthreads();   // sync2: C complete
    // ---- gather a2 jets + tanh + layer 3 + DPP wave reduction (no LDS pipe) ----
    float2 cv[5];
#pragma unroll
    for (int c = 0; c < 5; ++c)
      cv[c] = *(const float2*)(Cls + (c * PPB + p) * JSTRC + j0);
    float s[5];
#pragma unroll
    for (int c = 0; c < 5; ++c) s[c] = 0.0f;
#pragma unroll
    for (int jt = 0; jt < 2; ++jt) {
      Jet a2;
      a2.v  = (jt ? cv[0].y : cv[0].x) + b2a[jt];
      a2.w  = jt ? cv[1].y : cv[1].x;
      a2.y  = jt ? cv[2].y : cv[2].x;
      a2.ww = jt ? cv[3].y : cv[3].x;
      a2.wy = jt ? cv[4].y : cv[4].x;
      Jet hh = jtanh(a2);
      s[0] = fmaf(hh.v,  w3a[jt], s[0]);
      s[1] = fmaf(hh.w,  w3a[jt], s[1]);
      s[2] = fmaf(hh.y,  w3a[jt], s[2]);
      s[3] = fmaf(hh.ww, w3a[jt], s[3]);
      s[4] = fmaf(hh.wy, w3a[jt], s[4]);
    }
#pragma unroll
    for (int c = 0; c < 5; ++c) s[c] = wave_allsum(s[c]);
    Jet pi;
    pi.v = s[0] + b3r; pi.w = s[1]; pi.y = s[2]; pi.ww = s[3]; pi.wy = s[4];
    return pi;
  };

  // ---- initial state jets ----
  const float W0 = Wp[i];
  Jet L;
  L.v = __logf(fmaxf(W0, F_LBW));
  L.w = 1.0f / W0;
  L.y = 0.0f;
  L.ww = -1.0f / (W0 * W0);
  L.wy = 0.0f;
  Jet Yj;
  Yj.v = Yp[i]; Yj.w = 0.0f; Yj.y = 1.0f; Yj.ww = 0.0f; Yj.wy = 0.0f;
  float tmt = F_T;

  for (int m = 0; m < MSTEPS; ++m) {
    const float* nz = noise + (size_t)(m * 4) * BTOT + b;
    float z1b = nz[0];
    float z2b = nz[BTOT];
    float z1n = nz[2 * BTOT];
    float z2n = nz[3 * BTOT];
    float zWb = z1b, zYb = F_RHO * z1b + F_A * z2b;
    float zWn = z1n, zYn = F_RHO * z1n + F_A * z2n;
    float zWh1 = (zWb + zWn) * F_IS2, zYh1 = (zYb + zYn) * F_IS2;
    float zWh2 = (zWb - zWn) * F_IS2, zYh2 = (zYb - zYn) * F_IS2;

    Jet Win  = jexp(L);
    Jet pi_t = mlp(Win, tmt, Yj);

    Jet pY = jmul(pi_t, Yj);
    Jet pp = jmul(pi_t, pi_t);
    Jet dv = driftvar(pY, pp);

    float cWc  = F_SIG * (F_SDT * zWb);
    Jet lWc = jstep(L, dv, F_DT, pi_t, cWc);                      // coarse
    Jet Yc  = ydec(Yj, F_DT, F_SIGY * (F_SDT * zYb));

    float cWh1 = F_SIG * (F_SHALF * zWh1);
    Jet lWh = jstep(L, dv, F_HALF, pi_t, cWh1);                   // half 1
    Jet Yh  = ydec(Yj, F_HALF, F_SIGY * (F_SHALF * zYh1));

    Jet pih = mlp(jexp(lWh), tmt - F_HALF, Yh);                   // half 2
    Jet pYh = jmul(pih, Yh);
    Jet pph = jmul(pih, pih);
    Jet dvh = driftvar(pYh, pph);
    float cWh2 = F_SIG * (F_SHALF * zWh2);
    Jet lWf = jstep(lWh, dvh, F_HALF, pih, cWh2);
    Jet Yf  = ydec(Yh, F_HALF, F_SIGY * (F_SHALF * zYh2));

    // Richardson combination
    Jet raw, Yn;
    raw.v  = 2.0f * lWf.v  - lWc.v;
    raw.w  = 2.0f * lWf.w  - lWc.w;
    raw.y  = 2.0f * lWf.y  - lWc.y;
    raw.ww = 2.0f * lWf.ww - lWc.ww;
    raw.wy = 2.0f * lWf.wy - lWc.wy;
    Yn.v  = 2.0f * Yf.v  - Yc.v;
    Yn.w  = 2.0f * Yf.w  - Yc.w;
    Yn.y  = 2.0f * Yf.y  - Yc.y;
    Yn.ww = 2.0f * Yf.ww - Yc.ww;
    Yn.wy = 2.0f * Yf.wy - Yc.wy;

    // wealth floor: below log(LB_W) clamp value, zero derivatives
    bool ok = raw.v > F_LOGLBW;
    L.v  = ok ? raw.v  : F_LOGLBW;
    L.w  = ok ? raw.w  : 0.0f;
    L.y  = ok ? raw.y  : 0.0f;
    L.ww = ok ? raw.ww : 0.0f;
    L.wy = ok ? raw.wy : 0.0f;
    Yj = Yn;
    tmt -= F_DT;
  }

  // U = -0.25*exp(-4L); per-path dU/dW0, d2U/dW0^2, d2U/dW0dY0
  if (tl == 0) {
    float g = __expf(-4.0f * L.v);
    ws[b]            = g * L.w;
    ws[BTOT + b]     = g * (L.ww - 4.0f * L.w * L.w);
    ws[2 * BTOT + b] = g * (L.wy - 4.0f * L.w * L.y);
  }
}

__global__ void ppgdpo_reduce_kernel(const float* __restrict__ ws,
                                     const float* __restrict__ Wp,
                                     const float* __restrict__ Yp,
                                     float* __restrict__ out) {
  int i = threadIdx.x;  // 128 threads
  float sU = 0.f, sWW = 0.f, sWY = 0.f;
  for (int r = 0; r < RPTS; ++r) {
    int b = r * NPTS + i;
    sU  += ws[b];
    sWW += ws[BTOT + b];
    sWY += ws[2 * BTOT + b];
  }
  float lam = sU  * (1.0f / 32768.0f);
  float dW  = sWW * (1.0f / 1048576.0f);
  float dY  = sWY * (1.0f / 1048576.0f);

  float mu    = F_SIG * (0.8f * Yp[i]);
  float coeff = -1.0f / (Wp[i] * dW + 1e-8f);
  float myo   = coeff * (lam * (mu / F_S2));
  float hedge = coeff * ((float)(0.2 * 0.3 * 0.3) * dY / F_S2);
  float pi = myo + hedge;
  pi = fminf(fmaxf(pi, -2.0f), 2.0f);
  out[i] = pi;
}

extern "C" void kernel_launch(void* const* d_in, const int* in_sizes, int n_in,
                              void* d_out, int out_size, void* d_ws, size_t ws_size,
                              hipStream_t stream) {
  const float* W     = (const float*)d_in[0];
  const float* Y     = (const float*)d_in[2];
  const float* w1    = (const float*)d_in[3];
  const float* b1    = (const float*)d_in[4];
  const float* w2    = (const float*)d_in[5];
  const float* b2    = (const float*)d_in[6];
  const float* w3    = (const float*)d_in[7];
  const float* b3    = (const float*)d_in[8];
  const float* noise = (const float*)d_in[9];
  float* ws = (float*)d_ws;
  float* out = (float*)d_out;

  ppgdpo_sim_kernel<<<dim3(NBLK), dim3(512), 0, stream>>>(
      W, Y, w1, b1, w2, b2, w3, b3, noise, ws);
  ppgdpo_reduce_kernel<<<dim3(1), dim3(128), 0, stream>>>(ws, W, Y, out);
}

// Round 7
// 303.590 us; speedup vs baseline: 1.6160x; 1.0701x over previous
//
#include <hip/hip_runtime.h>
#include <hip/hip_bf16.h>
#include <math.h>

namespace {

constexpr int MSTEPS = 60;
constexpr int NPTS   = 128;
constexpr int RPTS   = 32;
constexpr int BTOT   = 4096;   // RPTS * NPTS
constexpr int HID    = 128;
constexpr int PPB    = 8;      // paths per block (2 per wave x 4 waves)
constexpr int NBLK   = BTOT / PPB;  // 512 blocks -> 2 per CU
constexpr int NCOLP  = 48;     // 40 cols (5 comps x 8 paths) padded to 3 tiles of 16
constexpr int STR    = 136;    // B row stride (bf16 elems), 272 B
constexpr int JSTRC  = 132;    // C row stride (f32), =4 mod 32

constexpr float F_T     = 1.5f;
constexpr float F_DT    = (float)(1.5 / 60.0);
constexpr float F_HALF  = (float)(0.5 * (1.5 / 60.0));
constexpr float F_SDT   = (float)0.15811388300841896659;  // sqrt(0.025)
constexpr float F_SHALF = (float)0.11180339887498948482;  // sqrt(0.0125)
constexpr float F_A     = (float)0.95393920141694565906;  // sqrt(1-0.3^2)
constexpr float F_IS2   = (float)0.70710678118654752440;
constexpr float F_R     = 0.02f;
constexpr float F_SIG   = 0.2f;
constexpr float F_SIGY  = 0.3f;
constexpr float F_RHO   = 0.3f;
constexpr float F_KY    = 1.2f;
constexpr float F_LBW   = 0.001f;
constexpr float F_LOGLBW = -6.90775527898213705205f;      // log(0.001)
constexpr float F_SA    = (float)(0.2 * 0.8);
constexpr float F_S2    = (float)(0.2 * 0.2);

typedef __attribute__((ext_vector_type(8))) short bf16x8;
typedef __attribute__((ext_vector_type(4))) float f32x4;

// RNE f32->bf16 (proven R3/R5)
__device__ __forceinline__ unsigned short f2bf(float x) {
  union { float f; unsigned u; } v; v.f = x;
  unsigned r = v.u + 0x7fffu + ((v.u >> 16) & 1u);
  return (unsigned short)(r >> 16);
}
__device__ __forceinline__ float bf2f(unsigned short h) {
  union { float f; unsigned u; } v; v.u = ((unsigned)h) << 16; return v.f;
}

// fast tanh: 1 - 2/(e^{2x}+1)
__device__ __forceinline__ float ftanh(float x) {
  float e = __expf(2.0f * x);
  return 1.0f - 2.0f / (e + 1.0f);
}

// x + dpp_perm(x); bound_ctrl=1 -> invalid lanes contribute 0  (proven R5)
template <int CTRL>
__device__ __forceinline__ float dpp_add(float x) {
  int y = __builtin_amdgcn_update_dpp(0, __float_as_int(x), CTRL, 0xf, 0xf, true);
  return x + __int_as_float(y);
}

// per-path (32-lane) all-sum: DPP row-of-16 tree (R5-proven) + xor-16 shuffle
// (R3-proven width-32 semantics). Lanes 0-31 get path-A sum, 32-63 path-B sum.
__device__ __forceinline__ float path_allsum(float x) {
  x = dpp_add<0xB1>(x);   // quad_perm xor1
  x = dpp_add<0x4E>(x);   // quad_perm xor2
  x = dpp_add<0x124>(x);  // row_ror:4
  x = dpp_add<0x128>(x);  // row_ror:8  -> row-of-16 sums
  x += __shfl_xor(x, 16, 32);
  return x;
}

// ---- 2nd-order jet: value, d/dW0, d/dY0, d2/dW0^2, d2/dW0dY0 ----
struct Jet { float v, w, y, ww, wy; };

__device__ __forceinline__ Jet jmul(const Jet& a, const Jet& b) {
  Jet r;
  r.v  = a.v * b.v;
  r.w  = a.v * b.w + a.w * b.v;
  r.y  = a.v * b.y + a.y * b.v;
  r.ww = a.v * b.ww + 2.0f * a.w * b.w + a.ww * b.v;
  r.wy = a.v * b.wy + a.w * b.y + a.y * b.w + a.wy * b.v;
  return r;
}

__device__ __forceinline__ Jet jexp(const Jet& a) {
  float e = __expf(a.v);
  Jet r;
  r.v  = e;
  r.w  = e * a.w;
  r.y  = e * a.y;
  r.ww = e * (a.ww + a.w * a.w);
  r.wy = e * (a.wy + a.w * a.y);
  return r;
}

__device__ __forceinline__ Jet jtanh(const Jet& a) {
  float t  = ftanh(a.v);
  float f1 = 1.0f - t * t;
  float f2 = -2.0f * t * f1;
  Jet r;
  r.v  = t;
  r.w  = f1 * a.w;
  r.y  = f1 * a.y;
  r.ww = f1 * a.ww + f2 * a.w * a.w;
  r.wy = f1 * a.wy + f2 * a.w * a.y;
  return r;
}

__device__ __forceinline__ Jet jstep(const Jet& base, const Jet& d, float cdt,
                                     const Jet& p, float cw) {
  Jet r;
  r.v  = base.v  + d.v  * cdt + p.v  * cw;
  r.w  = base.w  + d.w  * cdt + p.w  * cw;
  r.y  = base.y  + d.y  * cdt + p.y  * cw;
  r.ww = base.ww + d.ww * cdt + p.ww * cw;
  r.wy = base.wy + d.wy * cdt + p.wy * cw;
  return r;
}

__device__ __forceinline__ Jet ydec(const Jet& Y, float dt, float add) {
  Jet r;
  r.v  = Y.v  - F_KY * Y.v  * dt + add;
  r.w  = Y.w  - F_KY * Y.w  * dt;
  r.y  = Y.y  - F_KY * Y.y  * dt;
  r.ww = Y.ww - F_KY * Y.ww * dt;
  r.wy = Y.wy - F_KY * Y.wy * dt;
  return r;
}

__device__ __forceinline__ Jet driftvar(const Jet& pY, const Jet& pp) {
  Jet r;
  r.v  = F_R + F_SA * pY.v  - 0.5f * F_S2 * pp.v;
  r.w  =       F_SA * pY.w  - 0.5f * F_S2 * pp.w;
  r.y  =       F_SA * pY.y  - 0.5f * F_S2 * pp.y;
  r.ww =       F_SA * pY.ww - 0.5f * F_S2 * pp.ww;
  r.wy =       F_SA * pY.wy - 0.5f * F_S2 * pp.wy;
  return r;
}

} // namespace

// Block = 256 threads = 4 waves; 2 paths per wave (32 lanes each); 8 paths/block.
// Lane owns 4 hidden units j0=4*(ln&31) of its path. Wave owns 2 C row tiles.
// Layer 2: C[128][48] = (W2hi+W2lo)^T . Hbf16 via MFMA; C stored f32 (R5-proven).
__global__ __launch_bounds__(256, 2) void ppgdpo_sim_kernel(
    const float* __restrict__ Wp, const float* __restrict__ Yp,
    const float* __restrict__ w1, const float* __restrict__ b1,
    const float* __restrict__ w2, const float* __restrict__ b2,
    const float* __restrict__ w3, const float* __restrict__ b3,
    const float* __restrict__ noise, float* __restrict__ ws) {
  __shared__ __align__(16) unsigned short Bh[NCOLP * STR];  // 13,056 B (H bf16)
  __shared__ __align__(16) float Cls[NCOLP * JSTRC];        // 25,344 B (a2 f32)

  const int t    = threadIdx.x;
  const int wv   = t >> 6;           // wave id (0..3)
  const int ln   = t & 63;           // lane in wave
  const int lp   = ln & 31;          // lane in path
  const int pblk = wv * 2 + (ln >> 5);           // path in block (0..7)
  const int b    = blockIdx.x * PPB + pblk;      // global path (per-lane)
  const int i    = b & (NPTS - 1);

  const int bx = ln & 15;            // MFMA col-in-tile / A row-in-tile
  const int kg = ln >> 4;            // MFMA k-group (0..3)

  // ---- W2 -> A fragments for 2 row tiles, hi/lo split in registers ----
  bf16x8 Ah[2][4], Al[2][4];
#pragma unroll
  for (int rt = 0; rt < 2; ++rt) {
    const int arow = (wv * 2 + rt) * 16 + bx;
#pragma unroll
    for (int kt = 0; kt < 4; ++kt) {
#pragma unroll
      for (int q = 0; q < 8; ++q) {
        float wval = w2[(kt * 32 + kg * 8 + q) * HID + arow];
        unsigned short hi = f2bf(wval);
        unsigned short lo = f2bf(wval - bf2f(hi));
        Ah[rt][kt][q] = (short)hi;
        Al[rt][kt][q] = (short)lo;
      }
    }
  }

  // per-lane layer-1/3 weights for owned units j0..j0+3
  const int j0 = lp * 4;
  float w10[4], w11[4], w12[4], b1a[4], b2a[4], w3a[4];
  {
    float4 v;
    v = *(const float4*)(w1 + 0 * HID + j0); w10[0]=v.x; w10[1]=v.y; w10[2]=v.z; w10[3]=v.w;
    v = *(const float4*)(w1 + 1 * HID + j0); w11[0]=v.x; w11[1]=v.y; w11[2]=v.z; w11[3]=v.w;
    v = *(const float4*)(w1 + 2 * HID + j0); w12[0]=v.x; w12[1]=v.y; w12[2]=v.z; w12[3]=v.w;
    v = *(const float4*)(b1 + j0);           b1a[0]=v.x; b1a[1]=v.y; b1a[2]=v.z; b1a[3]=v.w;
    v = *(const float4*)(b2 + j0);           b2a[0]=v.x; b2a[1]=v.y; b2a[2]=v.z; b2a[3]=v.w;
    v = *(const float4*)(w3 + j0);           w3a[0]=v.x; w3a[1]=v.y; w3a[2]=v.z; w3a[3]=v.w;
  }
  const float b3r = b3[0];

  auto mlp = [&](const Jet& Win, float tsub, const Jet& Yin) -> Jet {
    // ---- layer 1: 4 owned units -> manual RNE bf16 pack -> one b64 write/comp ----
    Jet h[4];
#pragma unroll
    for (int u = 0; u < 4; ++u) {
      Jet a;
      a.v  = fmaf(w10[u], Win.v, fmaf(w11[u], tsub, fmaf(w12[u], Yin.v, b1a[u])));
      a.w  = fmaf(w10[u], Win.w,  w12[u] * Yin.w);
      a.y  = fmaf(w10[u], Win.y,  w12[u] * Yin.y);
      a.ww = fmaf(w10[u], Win.ww, w12[u] * Yin.ww);
      a.wy = fmaf(w10[u], Win.wy, w12[u] * Yin.wy);
      h[u] = jtanh(a);
    }
    {
      float c0[4] = {h[0].v,  h[1].v,  h[2].v,  h[3].v};
      float c1[4] = {h[0].w,  h[1].w,  h[2].w,  h[3].w};
      float c2[4] = {h[0].y,  h[1].y,  h[2].y,  h[3].y};
      float c3[4] = {h[0].ww, h[1].ww, h[2].ww, h[3].ww};
      float c4[4] = {h[0].wy, h[1].wy, h[2].wy, h[3].wy};
      const float* cc[5] = {c0, c1, c2, c3, c4};
#pragma unroll
      for (int c = 0; c < 5; ++c) {
        unsigned u0 = __float_as_uint(cc[c][0]);
        unsigned u1 = __float_as_uint(cc[c][1]);
        unsigned u2 = __float_as_uint(cc[c][2]);
        unsigned u3 = __float_as_uint(cc[c][3]);
        uint2 wj;
        wj.x = ((u0 + 0x7fffu + ((u0 >> 16) & 1u)) >> 16)
             | ((u1 + 0x7fffu + ((u1 >> 16) & 1u)) & 0xffff0000u);
        wj.y = ((u2 + 0x7fffu + ((u2 >> 16) & 1u)) >> 16)
             | ((u3 + 0x7fffu + ((u3 >> 16) & 1u)) & 0xffff0000u);
        *reinterpret_cast<uint2*>(&Bh[(c * PPB + pblk) * STR + j0]) = wj;
      }
    }
    __syncthreads();   // sync1: B complete (also: prev gather done before C overwrite)
    // ---- MFMA: 3 col tiles x (4 k tiles reused by 2 row tiles) x 2 split ----
#pragma unroll
    for (int ct = 0; ct < 3; ++ct) {
      bf16x8 bb[4];
#pragma unroll
      for (int kt = 0; kt < 4; ++kt)
        bb[kt] = *reinterpret_cast<const bf16x8*>(&Bh[(ct * 16 + bx) * STR + kt * 32 + kg * 8]);
#pragma unroll
      for (int rt = 0; rt < 2; ++rt) {
        f32x4 a_ = {0.f, 0.f, 0.f, 0.f};
#pragma unroll
        for (int kt = 0; kt < 4; ++kt) {
          a_ = __builtin_amdgcn_mfma_f32_16x16x32_bf16(Ah[rt][kt], bb[kt], a_, 0, 0, 0);
          a_ = __builtin_amdgcn_mfma_f32_16x16x32_bf16(Al[rt][kt], bb[kt], a_, 0, 0, 0);
        }
        *reinterpret_cast<f32x4*>(&Cls[(ct * 16 + bx) * JSTRC + (wv * 2 + rt) * 16 + kg * 4]) = a_;
      }
    }
    __syncthreads();   // sync2: C complete
    // ---- gather a2 (f32 float4) + tanh + layer 3 + per-path reduction ----
    float4 av[5];
#pragma unroll
    for (int c = 0; c < 5; ++c)
      av[c] = *reinterpret_cast<const float4*>(&Cls[(c * PPB + pblk) * JSTRC + j0]);
    float s[5] = {0.f, 0.f, 0.f, 0.f, 0.f};
#pragma unroll
    for (int u = 0; u < 4; ++u) {
      Jet a2;
      a2.v  = (u == 0 ? av[0].x : u == 1 ? av[0].y : u == 2 ? av[0].z : av[0].w) + b2a[u];
      a2.w  = (u == 0 ? av[1].x : u == 1 ? av[1].y : u == 2 ? av[1].z : av[1].w);
      a2.y  = (u == 0 ? av[2].x : u == 1 ? av[2].y : u == 2 ? av[2].z : av[2].w);
      a2.ww = (u == 0 ? av[3].x : u == 1 ? av[3].y : u == 2 ? av[3].z : av[3].w);
      a2.wy = (u == 0 ? av[4].x : u == 1 ? av[4].y : u == 2 ? av[4].z : av[4].w);
      Jet hh = jtanh(a2);
      s[0] = fmaf(hh.v,  w3a[u], s[0]);
      s[1] = fmaf(hh.w,  w3a[u], s[1]);
      s[2] = fmaf(hh.y,  w3a[u], s[2]);
      s[3] = fmaf(hh.ww, w3a[u], s[3]);
      s[4] = fmaf(hh.wy, w3a[u], s[4]);
    }
#pragma unroll
    for (int c = 0; c < 5; ++c) s[c] = path_allsum(s[c]);
    Jet pi;
    pi.v = s[0] + b3r; pi.w = s[1]; pi.y = s[2]; pi.ww = s[3]; pi.wy = s[4];
    return pi;
  };

  // ---- initial state jets (lanes of a path in lockstep) ----
  const float W0 = Wp[i];
  Jet L;
  L.v = __logf(fmaxf(W0, F_LBW));
  L.w = 1.0f / W0;
  L.y = 0.0f;
  L.ww = -1.0f / (W0 * W0);
  L.wy = 0.0f;
  Jet Yj;
  Yj.v = Yp[i]; Yj.w = 0.0f; Yj.y = 1.0f; Yj.ww = 0.0f; Yj.wy = 0.0f;
  float tmt = F_T;

  for (int m = 0; m < MSTEPS; ++m) {
    const float* nz = noise + (size_t)(m * 4) * BTOT + b;
    float z1b = nz[0];
    float z2b = nz[BTOT];
    float z1n = nz[2 * BTOT];
    float z2n = nz[3 * BTOT];
    float zWb = z1b, zYb = F_RHO * z1b + F_A * z2b;
    float zWn = z1n, zYn = F_RHO * z1n + F_A * z2n;
    float zWh1 = (zWb + zWn) * F_IS2, zYh1 = (zYb + zYn) * F_IS2;
    float zWh2 = (zWb - zWn) * F_IS2, zYh2 = (zYb - zYn) * F_IS2;

    Jet Win  = jexp(L);
    Jet pi_t = mlp(Win, tmt, Yj);

    Jet pY = jmul(pi_t, Yj);
    Jet pp = jmul(pi_t, pi_t);
    Jet dv = driftvar(pY, pp);

    float cWc  = F_SIG * (F_SDT * zWb);
    Jet lWc = jstep(L, dv, F_DT, pi_t, cWc);                      // coarse
    Jet Yc  = ydec(Yj, F_DT, F_SIGY * (F_SDT * zYb));

    float cWh1 = F_SIG * (F_SHALF * zWh1);
    Jet lWh = jstep(L, dv, F_HALF, pi_t, cWh1);                   // half 1
    Jet Yh  = ydec(Yj, F_HALF, F_SIGY * (F_SHALF * zYh1));

    Jet pih = mlp(jexp(lWh), tmt - F_HALF, Yh);                   // half 2
    Jet pYh = jmul(pih, Yh);
    Jet pph = jmul(pih, pih);
    Jet dvh = driftvar(pYh, pph);
    float cWh2 = F_SIG * (F_SHALF * zWh2);
    Jet lWf = jstep(lWh, dvh, F_HALF, pih, cWh2);
    Jet Yf  = ydec(Yh, F_HALF, F_SIGY * (F_SHALF * zYh2));

    // Richardson combination
    Jet raw, Yn;
    raw.v  = 2.0f * lWf.v  - lWc.v;
    raw.w  = 2.0f * lWf.w  - lWc.w;
    raw.y  = 2.0f * lWf.y  - lWc.y;
    raw.ww = 2.0f * lWf.ww - lWc.ww;
    raw.wy = 2.0f * lWf.wy - lWc.wy;
    Yn.v  = 2.0f * Yf.v  - Yc.v;
    Yn.w  = 2.0f * Yf.w  - Yc.w;
    Yn.y  = 2.0f * Yf.y  - Yc.y;
    Yn.ww = 2.0f * Yf.ww - Yc.ww;
    Yn.wy = 2.0f * Yf.wy - Yc.wy;

    // wealth floor: below log(LB_W) clamp value, zero derivatives
    bool ok = raw.v > F_LOGLBW;
    L.v  = ok ? raw.v  : F_LOGLBW;
    L.w  = ok ? raw.w  : 0.0f;
    L.y  = ok ? raw.y  : 0.0f;
    L.ww = ok ? raw.ww : 0.0f;
    L.wy = ok ? raw.wy : 0.0f;
    Yj = Yn;
    tmt -= F_DT;
  }

  // U = -0.25*exp(-4L); per-path dU/dW0, d2U/dW0^2, d2U/dW0dY0
  if (lp == 0) {
    float g = __expf(-4.0f * L.v);
    ws[b]            = g * L.w;
    ws[BTOT + b]     = g * (L.ww - 4.0f * L.w * L.w);
    ws[2 * BTOT + b] = g * (L.wy - 4.0f * L.w * L.y);
  }
}

__global__ void ppgdpo_reduce_kernel(const float* __restrict__ ws,
                                     const float* __restrict__ Wp,
                                     const float* __restrict__ Yp,
                                     float* __restrict__ out) {
  int i = threadIdx.x;  // 128 threads
  float sU = 0.f, sWW = 0.f, sWY = 0.f;
  for (int r = 0; r < RPTS; ++r) {
    int b = r * NPTS + i;
    sU  += ws[b];
    sWW += ws[BTOT + b];
    sWY += ws[2 * BTOT + b];
  }
  float lam = sU  * (1.0f / 32768.0f);
  float dW  = sWW * (1.0f / 1048576.0f);
  float dY  = sWY * (1.0f / 1048576.0f);

  float mu    = F_SIG * (0.8f * Yp[i]);
  float coeff = -1.0f / (Wp[i] * dW + 1e-8f);
  float myo   = coeff * (lam * (mu / F_S2));
  float hedge = coeff * ((float)(0.2 * 0.3 * 0.3) * dY / F_S2);
  float pi = myo + hedge;
  pi = fminf(fmaxf(pi, -2.0f), 2.0f);
  out[i] = pi;
}

extern "C" void kernel_launch(void* const* d_in, const int* in_sizes, int n_in,
                              void* d_out, int out_size, void* d_ws, size_t ws_size,
                              hipStream_t stream) {
  const float* W     = (const float*)d_in[0];
  const float* Y     = (const float*)d_in[2];
  const float* w1    = (const float*)d_in[3];
  const float* b1    = (const float*)d_in[4];
  const float* w2    = (const float*)d_in[5];
  const float* b2    = (const float*)d_in[6];
  const float* w3    = (const float*)d_in[7];
  const float* b3    = (const float*)d_in[8];
  const float* noise = (const float*)d_in[9];
  float* ws = (float*)d_ws;
  float* out = (float*)d_out;

  ppgdpo_sim_kernel<<<dim3(NBLK), dim3(256), 0, stream>>>(
      W, Y, w1, b1, w2, b2, w3, b3, noise, ws);
  ppgdpo_reduce_kernel<<<dim3(1), dim3(128), 0, stream>>>(ws, W, Y, out);
}

// Round 8
// 271.100 us; speedup vs baseline: 1.8096x; 1.1198x over previous
//
#include <hip/hip_runtime.h>
#include <hip/hip_bf16.h>
#include <math.h>

namespace {

constexpr int MSTEPS = 60;
constexpr int NPTS   = 128;
constexpr int RPTS   = 32;
constexpr int BTOT   = 4096;   // RPTS * NPTS
constexpr int HID    = 128;
constexpr int PPB    = 8;      // paths per block (2 per wave x 4 waves)
constexpr int NBLK   = BTOT / PPB;  // 512 blocks -> 2 per CU
constexpr int STR    = 136;    // B row stride (bf16 elems), 272 B
constexpr int JSTRC  = 132;    // C row stride (f32), =4 mod 32

constexpr float F_T     = 1.5f;
constexpr float F_DT    = (float)(1.5 / 60.0);
constexpr float F_HALF  = (float)(0.5 * (1.5 / 60.0));
constexpr float F_SDT   = (float)0.15811388300841896659;  // sqrt(0.025)
constexpr float F_SHALF = (float)0.11180339887498948482;  // sqrt(0.0125)
constexpr float F_A     = (float)0.95393920141694565906;  // sqrt(1-0.3^2)
constexpr float F_IS2   = (float)0.70710678118654752440;
constexpr float F_R     = 0.02f;
constexpr float F_SIG   = 0.2f;
constexpr float F_SIGY  = 0.3f;
constexpr float F_RHO   = 0.3f;
constexpr float F_KY    = 1.2f;
constexpr float F_LBW   = 0.001f;
constexpr float F_LOGLBW = -6.90775527898213705205f;      // log(0.001)
constexpr float F_SA    = (float)(0.2 * 0.8);
constexpr float F_S2    = (float)(0.2 * 0.2);

typedef __attribute__((ext_vector_type(8))) short bf16x8;
typedef __attribute__((ext_vector_type(4))) float f32x4;

// RNE f32->bf16 (proven R3/R5/R7)
__device__ __forceinline__ unsigned short f2bf(float x) {
  union { float f; unsigned u; } v; v.f = x;
  unsigned r = v.u + 0x7fffu + ((v.u >> 16) & 1u);
  return (unsigned short)(r >> 16);
}

// fast tanh: 1 - 2/(e^{2x}+1)
__device__ __forceinline__ float ftanh(float x) {
  float e = __expf(2.0f * x);
  return 1.0f - 2.0f / (e + 1.0f);
}

// x + dpp_perm(x); bound_ctrl=1 -> invalid lanes contribute 0  (proven R5/R7)
template <int CTRL>
__device__ __forceinline__ float dpp_add(float x) {
  int y = __builtin_amdgcn_update_dpp(0, __float_as_int(x), CTRL, 0xf, 0xf, true);
  return x + __int_as_float(y);
}

// per-path (32-lane) all-sum: DPP row-of-16 tree + xor-16 shuffle (proven R7).
__device__ __forceinline__ float path_allsum(float x) {
  x = dpp_add<0xB1>(x);   // quad_perm xor1
  x = dpp_add<0x4E>(x);   // quad_perm xor2
  x = dpp_add<0x124>(x);  // row_ror:4
  x = dpp_add<0x128>(x);  // row_ror:8  -> row-of-16 sums
  x += __shfl_xor(x, 16, 32);
  return x;
}

// ---- 2nd-order jet: value, d/dW0, d/dY0, d2/dW0^2, d2/dW0dY0 ----
struct Jet { float v, w, y, ww, wy; };

__device__ __forceinline__ Jet jmul(const Jet& a, const Jet& b) {
  Jet r;
  r.v  = a.v * b.v;
  r.w  = a.v * b.w + a.w * b.v;
  r.y  = a.v * b.y + a.y * b.v;
  r.ww = a.v * b.ww + 2.0f * a.w * b.w + a.ww * b.v;
  r.wy = a.v * b.wy + a.w * b.y + a.y * b.w + a.wy * b.v;
  return r;
}

__device__ __forceinline__ Jet jexp(const Jet& a) {
  float e = __expf(a.v);
  Jet r;
  r.v  = e;
  r.w  = e * a.w;
  r.y  = e * a.y;
  r.ww = e * (a.ww + a.w * a.w);
  r.wy = e * (a.wy + a.w * a.y);
  return r;
}

__device__ __forceinline__ Jet jtanh(const Jet& a) {
  float t  = ftanh(a.v);
  float f1 = 1.0f - t * t;
  float f2 = -2.0f * t * f1;
  Jet r;
  r.v  = t;
  r.w  = f1 * a.w;
  r.y  = f1 * a.y;
  r.ww = f1 * a.ww + f2 * a.w * a.w;
  r.wy = f1 * a.wy + f2 * a.w * a.y;
  return r;
}

__device__ __forceinline__ Jet jstep(const Jet& base, const Jet& d, float cdt,
                                     const Jet& p, float cw) {
  Jet r;
  r.v  = base.v  + d.v  * cdt + p.v  * cw;
  r.w  = base.w  + d.w  * cdt + p.w  * cw;
  r.y  = base.y  + d.y  * cdt + p.y  * cw;
  r.ww = base.ww + d.ww * cdt + p.ww * cw;
  r.wy = base.wy + d.wy * cdt + p.wy * cw;
  return r;
}

__device__ __forceinline__ Jet ydec(const Jet& Y, float dt, float add) {
  Jet r;
  r.v  = Y.v  - F_KY * Y.v  * dt + add;
  r.w  = Y.w  - F_KY * Y.w  * dt;
  r.y  = Y.y  - F_KY * Y.y  * dt;
  r.ww = Y.ww - F_KY * Y.ww * dt;
  r.wy = Y.wy - F_KY * Y.wy * dt;
  return r;
}

__device__ __forceinline__ Jet driftvar(const Jet& pY, const Jet& pp) {
  Jet r;
  r.v  = F_R + F_SA * pY.v  - 0.5f * F_S2 * pp.v;
  r.w  =       F_SA * pY.w  - 0.5f * F_S2 * pp.w;
  r.y  =       F_SA * pY.y  - 0.5f * F_S2 * pp.y;
  r.ww =       F_SA * pY.ww - 0.5f * F_S2 * pp.ww;
  r.wy =       F_SA * pY.wy - 0.5f * F_S2 * pp.wy;
  return r;
}

} // namespace

// WAVE-AUTONOMOUS: each wave owns 2 paths and computes their FULL layer-2 GEMM
// C[128 rows][16 cols] (cols 0-9 = 2 paths x 5 jet comps) with W2 (bf16, single)
// held as 8 row-tile A-fragments in registers. B and C live in wave-PRIVATE LDS;
// producer == consumer wave, same-wave DS ops are in-order -> ZERO __syncthreads.
__global__ __launch_bounds__(256, 2) void ppgdpo_sim_kernel(
    const float* __restrict__ Wp, const float* __restrict__ Yp,
    const float* __restrict__ w1, const float* __restrict__ b1,
    const float* __restrict__ w2, const float* __restrict__ b2,
    const float* __restrict__ w3, const float* __restrict__ b3,
    const float* __restrict__ noise, float* __restrict__ ws) {
  __shared__ __align__(16) unsigned short Bsh[4][16 * STR];   // 17,408 B
  __shared__ __align__(16) float Csh[4][16 * JSTRC];          // 33,792 B

  const int t    = threadIdx.x;
  const int wv   = t >> 6;           // wave id (0..3)
  const int ln   = t & 63;           // lane in wave
  const int lp   = ln & 31;          // lane in path
  const int ph   = ln >> 5;          // path in wave (0/1)
  const int pblk = wv * 2 + ph;      // path in block
  const int b    = blockIdx.x * PPB + pblk;
  const int i    = b & (NPTS - 1);

  const int bx = ln & 15;            // MFMA col / A-row in tile
  const int kg = ln >> 4;            // MFMA k-group (0..3)

  // ---- W2 -> A fragments for ALL 8 row tiles (bf16, registers, once) ----
  bf16x8 A[8][4];
#pragma unroll
  for (int rt = 0; rt < 8; ++rt) {
#pragma unroll
    for (int kt = 0; kt < 4; ++kt) {
#pragma unroll
      for (int q = 0; q < 8; ++q)
        A[rt][kt][q] = (short)f2bf(w2[(kt * 32 + kg * 8 + q) * HID + rt * 16 + bx]);
    }
  }

  // per-lane layer-1/3 weights for owned units j0..j0+3 of this lane's path
  const int j0 = lp * 4;
  float w10[4], w11[4], w12[4], b1a[4], b2a[4], w3a[4];
  {
    float4 v;
    v = *(const float4*)(w1 + 0 * HID + j0); w10[0]=v.x; w10[1]=v.y; w10[2]=v.z; w10[3]=v.w;
    v = *(const float4*)(w1 + 1 * HID + j0); w11[0]=v.x; w11[1]=v.y; w11[2]=v.z; w11[3]=v.w;
    v = *(const float4*)(w1 + 2 * HID + j0); w12[0]=v.x; w12[1]=v.y; w12[2]=v.z; w12[3]=v.w;
    v = *(const float4*)(b1 + j0);           b1a[0]=v.x; b1a[1]=v.y; b1a[2]=v.z; b1a[3]=v.w;
    v = *(const float4*)(b2 + j0);           b2a[0]=v.x; b2a[1]=v.y; b2a[2]=v.z; b2a[3]=v.w;
    v = *(const float4*)(w3 + j0);           w3a[0]=v.x; w3a[1]=v.y; w3a[2]=v.z; w3a[3]=v.w;
  }
  const float b3r = b3[0];

  unsigned short* const myB = Bsh[wv];   // wave-private
  float* const myC = Csh[wv];            // wave-private
  const int cb = ph * 5;                 // this path's col base (0 or 5)

  auto mlp = [&](const Jet& Win, float tsub, const Jet& Yin) -> Jet {
    // ---- layer 1: 4 owned units -> RNE bf16 pack -> b64 write per comp ----
    Jet h[4];
#pragma unroll
    for (int u = 0; u < 4; ++u) {
      Jet a;
      a.v  = fmaf(w10[u], Win.v, fmaf(w11[u], tsub, fmaf(w12[u], Yin.v, b1a[u])));
      a.w  = fmaf(w10[u], Win.w,  w12[u] * Yin.w);
      a.y  = fmaf(w10[u], Win.y,  w12[u] * Yin.y);
      a.ww = fmaf(w10[u], Win.ww, w12[u] * Yin.ww);
      a.wy = fmaf(w10[u], Win.wy, w12[u] * Yin.wy);
      h[u] = jtanh(a);
    }
    {
      float c0[4] = {h[0].v,  h[1].v,  h[2].v,  h[3].v};
      float c1[4] = {h[0].w,  h[1].w,  h[2].w,  h[3].w};
      float c2[4] = {h[0].y,  h[1].y,  h[2].y,  h[3].y};
      float c3[4] = {h[0].ww, h[1].ww, h[2].ww, h[3].ww};
      float c4[4] = {h[0].wy, h[1].wy, h[2].wy, h[3].wy};
      const float* cc[5] = {c0, c1, c2, c3, c4};
#pragma unroll
      for (int c = 0; c < 5; ++c) {
        unsigned u0 = __float_as_uint(cc[c][0]);
        unsigned u1 = __float_as_uint(cc[c][1]);
        unsigned u2 = __float_as_uint(cc[c][2]);
        unsigned u3 = __float_as_uint(cc[c][3]);
        uint2 wj;
        wj.x = ((u0 + 0x7fffu + ((u0 >> 16) & 1u)) >> 16)
             | ((u1 + 0x7fffu + ((u1 >> 16) & 1u)) & 0xffff0000u);
        wj.y = ((u2 + 0x7fffu + ((u2 >> 16) & 1u)) >> 16)
             | ((u3 + 0x7fffu + ((u3 >> 16) & 1u)) & 0xffff0000u);
        *reinterpret_cast<uint2*>(&myB[(cb + c) * STR + j0]) = wj;
      }
    }
    // (no barrier: same-wave DS ops are in-order)
    // ---- MFMA: 8 row tiles x 4 k tiles, single bf16 W2 ----
    bf16x8 bb[4];
#pragma unroll
    for (int kt = 0; kt < 4; ++kt)
      bb[kt] = *reinterpret_cast<const bf16x8*>(&myB[bx * STR + kt * 32 + kg * 8]);
#pragma unroll
    for (int rt = 0; rt < 8; ++rt) {
      f32x4 a_ = {0.f, 0.f, 0.f, 0.f};
#pragma unroll
      for (int kt = 0; kt < 4; ++kt)
        a_ = __builtin_amdgcn_mfma_f32_16x16x32_bf16(A[rt][kt], bb[kt], a_, 0, 0, 0);
      *reinterpret_cast<f32x4*>(&myC[bx * JSTRC + rt * 16 + kg * 4]) = a_;
    }
    // (no barrier)
    // ---- gather a2 (f32 float4) + tanh + layer 3 + per-path reduction ----
    float4 av[5];
#pragma unroll
    for (int c = 0; c < 5; ++c)
      av[c] = *reinterpret_cast<const float4*>(&myC[(cb + c) * JSTRC + j0]);
    float s[5] = {0.f, 0.f, 0.f, 0.f, 0.f};
#pragma unroll
    for (int u = 0; u < 4; ++u) {
      Jet a2;
      a2.v  = (u == 0 ? av[0].x : u == 1 ? av[0].y : u == 2 ? av[0].z : av[0].w) + b2a[u];
      a2.w  = (u == 0 ? av[1].x : u == 1 ? av[1].y : u == 2 ? av[1].z : av[1].w);
      a2.y  = (u == 0 ? av[2].x : u == 1 ? av[2].y : u == 2 ? av[2].z : av[2].w);
      a2.ww = (u == 0 ? av[3].x : u == 1 ? av[3].y : u == 2 ? av[3].z : av[3].w);
      a2.wy = (u == 0 ? av[4].x : u == 1 ? av[4].y : u == 2 ? av[4].z : av[4].w);
      Jet hh = jtanh(a2);
      s[0] = fmaf(hh.v,  w3a[u], s[0]);
      s[1] = fmaf(hh.w,  w3a[u], s[1]);
      s[2] = fmaf(hh.y,  w3a[u], s[2]);
      s[3] = fmaf(hh.ww, w3a[u], s[3]);
      s[4] = fmaf(hh.wy, w3a[u], s[4]);
    }
#pragma unroll
    for (int c = 0; c < 5; ++c) s[c] = path_allsum(s[c]);
    Jet pi;
    pi.v = s[0] + b3r; pi.w = s[1]; pi.y = s[2]; pi.ww = s[3]; pi.wy = s[4];
    return pi;
  };

  // ---- initial state jets (lanes of a path in lockstep) ----
  const float W0 = Wp[i];
  Jet L;
  L.v = __logf(fmaxf(W0, F_LBW));
  L.w = 1.0f / W0;
  L.y = 0.0f;
  L.ww = -1.0f / (W0 * W0);
  L.wy = 0.0f;
  Jet Yj;
  Yj.v = Yp[i]; Yj.w = 0.0f; Yj.y = 1.0f; Yj.ww = 0.0f; Yj.wy = 0.0f;
  float tmt = F_T;

  for (int m = 0; m < MSTEPS; ++m) {
    const float* nz = noise + (size_t)(m * 4) * BTOT + b;
    float z1b = nz[0];
    float z2b = nz[BTOT];
    float z1n = nz[2 * BTOT];
    float z2n = nz[3 * BTOT];
    float zWb = z1b, zYb = F_RHO * z1b + F_A * z2b;
    float zWn = z1n, zYn = F_RHO * z1n + F_A * z2n;
    float zWh1 = (zWb + zWn) * F_IS2, zYh1 = (zYb + zYn) * F_IS2;
    float zWh2 = (zWb - zWn) * F_IS2, zYh2 = (zYb - zYn) * F_IS2;

    Jet Win  = jexp(L);
    Jet pi_t = mlp(Win, tmt, Yj);

    Jet pY = jmul(pi_t, Yj);
    Jet pp = jmul(pi_t, pi_t);
    Jet dv = driftvar(pY, pp);

    float cWc  = F_SIG * (F_SDT * zWb);
    Jet lWc = jstep(L, dv, F_DT, pi_t, cWc);                      // coarse
    Jet Yc  = ydec(Yj, F_DT, F_SIGY * (F_SDT * zYb));

    float cWh1 = F_SIG * (F_SHALF * zWh1);
    Jet lWh = jstep(L, dv, F_HALF, pi_t, cWh1);                   // half 1
    Jet Yh  = ydec(Yj, F_HALF, F_SIGY * (F_SHALF * zYh1));

    Jet pih = mlp(jexp(lWh), tmt - F_HALF, Yh);                   // half 2
    Jet pYh = jmul(pih, Yh);
    Jet pph = jmul(pih, pih);
    Jet dvh = driftvar(pYh, pph);
    float cWh2 = F_SIG * (F_SHALF * zWh2);
    Jet lWf = jstep(lWh, dvh, F_HALF, pih, cWh2);
    Jet Yf  = ydec(Yh, F_HALF, F_SIGY * (F_SHALF * zYh2));

    // Richardson combination
    Jet raw, Yn;
    raw.v  = 2.0f * lWf.v  - lWc.v;
    raw.w  = 2.0f * lWf.w  - lWc.w;
    raw.y  = 2.0f * lWf.y  - lWc.y;
    raw.ww = 2.0f * lWf.ww - lWc.ww;
    raw.wy = 2.0f * lWf.wy - lWc.wy;
    Yn.v  = 2.0f * Yf.v  - Yc.v;
    Yn.w  = 2.0f * Yf.w  - Yc.w;
    Yn.y  = 2.0f * Yf.y  - Yc.y;
    Yn.ww = 2.0f * Yf.ww - Yc.ww;
    Yn.wy = 2.0f * Yf.wy - Yc.wy;

    // wealth floor: below log(LB_W) clamp value, zero derivatives
    bool ok = raw.v > F_LOGLBW;
    L.v  = ok ? raw.v  : F_LOGLBW;
    L.w  = ok ? raw.w  : 0.0f;
    L.y  = ok ? raw.y  : 0.0f;
    L.ww = ok ? raw.ww : 0.0f;
    L.wy = ok ? raw.wy : 0.0f;
    Yj = Yn;
    tmt -= F_DT;
  }

  // U = -0.25*exp(-4L); per-path dU/dW0, d2U/dW0^2, d2U/dW0dY0
  if (lp == 0) {
    float g = __expf(-4.0f * L.v);
    ws[b]            = g * L.w;
    ws[BTOT + b]     = g * (L.ww - 4.0f * L.w * L.w);
    ws[2 * BTOT + b] = g * (L.wy - 4.0f * L.w * L.y);
  }
}

__global__ void ppgdpo_reduce_kernel(const float* __restrict__ ws,
                                     const float* __restrict__ Wp,
                                     const float* __restrict__ Yp,
                                     float* __restrict__ out) {
  int i = threadIdx.x;  // 128 threads
  float sU = 0.f, sWW = 0.f, sWY = 0.f;
  for (int r = 0; r < RPTS; ++r) {
    int b = r * NPTS + i;
    sU  += ws[b];
    sWW += ws[BTOT + b];
    sWY += ws[2 * BTOT + b];
  }
  float lam = sU  * (1.0f / 32768.0f);
  float dW  = sWW * (1.0f / 1048576.0f);
  float dY  = sWY * (1.0f / 1048576.0f);

  float mu    = F_SIG * (0.8f * Yp[i]);
  float coeff = -1.0f / (Wp[i] * dW + 1e-8f);
  float myo   = coeff * (lam * (mu / F_S2));
  float hedge = coeff * ((float)(0.2 * 0.3 * 0.3) * dY / F_S2);
  float pi = myo + hedge;
  pi = fminf(fmaxf(pi, -2.0f), 2.0f);
  out[i] = pi;
}

extern "C" void kernel_launch(void* const* d_in, const int* in_sizes, int n_in,
                              void* d_out, int out_size, void* d_ws, size_t ws_size,
                              hipStream_t stream) {
  const float* W     = (const float*)d_in[0];
  const float* Y     = (const float*)d_in[2];
  const float* w1    = (const float*)d_in[3];
  const float* b1    = (const float*)d_in[4];
  const float* w2    = (const float*)d_in[5];
  const float* b2    = (const float*)d_in[6];
  const float* w3    = (const float*)d_in[7];
  const float* b3    = (const float*)d_in[8];
  const float* noise = (const float*)d_in[9];
  float* ws = (float*)d_ws;
  float* out = (float*)d_out;

  ppgdpo_sim_kernel<<<dim3(NBLK), dim3(256), 0, stream>>>(
      W, Y, w1, b1, w2, b2, w3, b3, noise, ws);
  ppgdpo_reduce_kernel<<<dim3(1), dim3(128), 0, stream>>>(ws, W, Y, out);
}